// Round 13
// baseline (77.215 us; speedup 1.0000x reference)
//
#include <hip/hip_runtime.h>

namespace {
constexpr int Bv = 8;
constexpr int Nv = 2048;
constexpr int Dv = 256;
constexpr float SCALE = 0.1f;
constexpr float PSCALE = 256.0f;          // P quant scale (fp8 normal range)
constexpr float OSC = SCALE / PSCALE;     // epilogue un-scale
constexpr float LN_EPS = 1e-6f;
constexpr float NORM_EPS = 1e-12f;
}

typedef unsigned char u8;
typedef unsigned int u32;
typedef __attribute__((ext_vector_type(4))) float f32x4;

// global -> LDS direct DMA, 16B/lane. lds base wave-uniform; HW adds lane*16.
__device__ __forceinline__ void gll16(const void* g, void* l) {
    __builtin_amdgcn_global_load_lds(
        (__attribute__((address_space(1))) void*)(uintptr_t)g,
        (__attribute__((address_space(3))) void*)(uintptr_t)l, 16, 0, 0);
}
// pack 4 f32 -> 4 fp8 e4m3 bytes
__device__ __forceinline__ u32 pk4(float a, float b, float c, float d) {
    u32 w = __builtin_amdgcn_cvt_pk_fp8_f32(a, b, 0, false);
    return __builtin_amdgcn_cvt_pk_fp8_f32(c, d, w, true);
}

// ---------------------------------------------------------------------------
// 1) Fused prep. Outputs: xn8 row-major fp8 (L2-normalized rows) and
//    xT8 row-major fp8 (raw x transposed, [b][d][n]). Block = 64 rows x 256 d.
__global__ __launch_bounds__(512) void k_prepT(const float* __restrict__ x,
                                               u8* __restrict__ xn8,
                                               u8* __restrict__ xT8) {
    __shared__ u8 lt[64][272];   // raw-x fp8 [n_local][d]
    const int b = blockIdx.x >> 5;
    const int n0 = (blockIdx.x & 31) * 64;
    const int t = threadIdx.x;
    const int r = t >> 3, c0 = (t & 7) * 32;
    const float* xr = x + ((size_t)b * Nv + n0 + r) * Dv + c0;
    float4 v[8];
    float ss = 0.f;
#pragma unroll
    for (int i = 0; i < 8; ++i) {
        v[i] = ((const float4*)xr)[i];
        ss += v[i].x * v[i].x + v[i].y * v[i].y + v[i].z * v[i].z + v[i].w * v[i].w;
    }
#pragma unroll
    for (int m = 1; m < 8; m <<= 1) ss += __shfl_xor(ss, m, 64);
    const float inv = 1.0f / fmaxf(sqrtf(ss), NORM_EPS);
    u32 wn[8];
#pragma unroll
    for (int i = 0; i < 8; ++i) {
        wn[i] = pk4(v[i].x * inv, v[i].y * inv, v[i].z * inv, v[i].w * inv);
        *(u32*)&lt[r][c0 + i * 4] = pk4(v[i].x, v[i].y, v[i].z, v[i].w);
    }
    {   // xn8 row-major
        uint4 o0 = {wn[0], wn[1], wn[2], wn[3]};
        uint4 o1 = {wn[4], wn[5], wn[6], wn[7]};
        u8* xnr = xn8 + ((size_t)b * Nv + n0 + r) * Dv + c0;
        *(uint4*)xnr = o0;
        *(uint4*)(xnr + 16) = o1;
    }
    __syncthreads();
    {   // xT8 row-major [d][n]: thread handles d = t>>1, n-half h = t&1
        const int d = t >> 1, h = t & 1;
        u32 w2[8];
#pragma unroll
        for (int q = 0; q < 8; ++q) {
            const int nb = h * 32 + q * 4;
            w2[q] = (u32)lt[nb][d] | ((u32)lt[nb + 1][d] << 8) |
                    ((u32)lt[nb + 2][d] << 16) | ((u32)lt[nb + 3][d] << 24);
        }
        uint4 p0 = {w2[0], w2[1], w2[2], w2[3]};
        uint4 p1 = {w2[4], w2[5], w2[6], w2[7]};
        u8* xtr = xT8 + ((size_t)b * Dv + d) * Nv + n0 + h * 32;
        *(uint4*)xtr = p0;
        *(uint4*)(xtr + 16) = p1;
    }
}

// ---------------------------------------------------------------------------
// 2) E = exp(xn@xn^T - 1) fp8, 64-row panels x all 2048 cols, 512 thr,
//    waves 2(row) x 4(col), wave tile 32x32, A-frags in registers.
//    B gll16-staged dbuf (128 rows x 256B, slot^(row&15)). Single eS
//    (stride 80, 16B-aligned). rl written directly (no atomics).
__global__ __launch_bounds__(512) void k_gemm1(const u8* __restrict__ xn8,
                                               u8* __restrict__ E,
                                               float* __restrict__ rl) {
    __shared__ u8 Bs[2][128 * 256];   // 64 KB
    __shared__ u8 eS[128 * 80];       // 10 KB  [m-col][64 n + pad16]
    __shared__ float red[64][4];      // 1 KB
    const int wg = blockIdx.x;        // 256: XCD owns one batch
    const int b = wg & 7, bi = wg >> 3;            // bi 0..31 (64-row panel)
    const int t = threadIdx.x;
    const int wave = t >> 6, lane = t & 63;
    const int wrp = wave >> 2, wc = wave & 3;      // wave tile 32r x 32c
    const int l15 = lane & 15, kl = lane >> 4;
    const u8* xb = xn8 + (size_t)b * (Nv * Dv);
    u8* Eb = E + (size_t)b * Nv * Nv;

    auto stageB = [&](int buf, int ch) {   // 128 rows x 256B, swizzled source
#pragma unroll
        for (int c = 0; c < 4; ++c) {
            const int row = wave * 16 + c * 4 + (lane >> 4);
            const int slot = (lane & 15) ^ (row & 15);
            gll16(xb + (size_t)(ch * 128 + row) * Dv + slot * 16,
                  Bs[buf] + wave * 4096 + c * 1024);
        }
    };
    auto bfrag = [&](const u8* base, int row, int kk) -> long {
        const int slot = kk * 2 + (kl >> 1);
        return *(const long*)(base + row * 256 +
                              ((slot ^ (row & 15)) << 4) + ((kl & 1) << 3));
    };

    const int ch0 = bi >> 1;   // chunk containing this panel's rows
    stageB(0, ch0);
    __syncthreads();
    long af[2][8];
    {
#pragma unroll
        for (int i = 0; i < 2; ++i) {
            const int arow = (bi & 1) * 64 + wrp * 32 + i * 16 + l15;
#pragma unroll
            for (int kk = 0; kk < 8; ++kk) af[i][kk] = bfrag(Bs[0], arow, kk);
        }
    }
    stageB(1, (ch0 + 1) & 15);
    __syncthreads();

    float rs[2][4] = {};
    for (int cc = 0; cc < 16; ++cc) {
        const int ch = (ch0 + cc) & 15;
        const int cur = cc & 1;
        // phase 1: MFMA + exp -> eS
        f32x4 acc[2][2] = {};
#pragma unroll
        for (int kk = 0; kk < 8; ++kk) {
            const long b0 = bfrag(Bs[cur], wc * 32 + l15, kk);
            const long b1 = bfrag(Bs[cur], wc * 32 + 16 + l15, kk);
#pragma unroll
            for (int i = 0; i < 2; ++i) {
                acc[i][0] = __builtin_amdgcn_mfma_f32_16x16x32_fp8_fp8(af[i][kk], b0, acc[i][0], 0, 0, 0);
                acc[i][1] = __builtin_amdgcn_mfma_f32_16x16x32_fp8_fp8(af[i][kk], b1, acc[i][1], 0, 0, 0);
            }
        }
#pragma unroll
        for (int i = 0; i < 2; ++i) {
#pragma unroll
            for (int j = 0; j < 2; ++j) {
                const int col = wc * 32 + j * 16 + l15;
                const float e0 = __expf(acc[i][j][0] - 1.0f);
                const float e1 = __expf(acc[i][j][1] - 1.0f);
                const float e2 = __expf(acc[i][j][2] - 1.0f);
                const float e3 = __expf(acc[i][j][3] - 1.0f);
                rs[i][0] += e0; rs[i][1] += e1; rs[i][2] += e2; rs[i][3] += e3;
                *(u32*)&eS[col * 80 + wrp * 32 + i * 16 + kl * 4] = pk4(e0, e1, e2, e3);
            }
        }
        __syncthreads();
        // phase 2: E-store + stage chunk cc+2
        {
            const int m = t >> 2, q = t & 3;
            *(uint4*)&Eb[(size_t)(ch * 128 + m) * Nv + bi * 64 + q * 16] =
                *(const uint4*)&eS[m * 80 + q * 16];
        }
        if (cc < 14) stageB(cur, (ch0 + cc + 2) & 15);
        __syncthreads();
    }
    // rl reduction: plain write, no atomics.
#pragma unroll
    for (int i = 0; i < 2; ++i)
#pragma unroll
        for (int r = 0; r < 4; ++r) {
            float v = rs[i][r];
#pragma unroll
            for (int m = 1; m < 16; m <<= 1) v += __shfl_xor(v, m, 64);
            if (l15 == 0) red[wrp * 32 + i * 16 + kl * 4 + r][wc] = v;
        }
    __syncthreads();
    if (t < 64)
        rl[b * Nv + bi * 64 + t] =
            PSCALE * __builtin_amdgcn_rcpf(red[t][0] + red[t][1] + red[t][2] + red[t][3]);
}

// ---------------------------------------------------------------------------
// 3) x_neg = P @ x, P[n,m] = E[n,m]*(rl_n + rl_m), fused LN epilogue.
//    64-row panels, 512 thr, waves 2(row) x 4(col), wave tile 32x64
//    (acc[2][4]). Single Ps (stride 144, 16B-aligned), Bs dbuf (256x128B,
//    slot^(row&7)). E/rl prefetched into regs during MFMA phase.
__global__ __launch_bounds__(512) void k_gemm2ln(const u8* __restrict__ E,
                                                 const float* __restrict__ rl,
                                                 const u8* __restrict__ xT8,
                                                 const float* __restrict__ x,
                                                 const float* __restrict__ gamma,
                                                 const float* __restrict__ beta,
                                                 float* __restrict__ out) {
    __shared__ u8 Bs[2][256 * 128];   // 64 KB
    __shared__ u8 Ps[64 * 144];       // 9 KB
    const int wg = blockIdx.x;        // 256: XCD owns one batch
    const int swz = (wg & 7) * 32 + (wg >> 3);
    const int b = swz >> 5, bi = swz & 31;         // 64-row panel
    const int t = threadIdx.x;
    const int wave = t >> 6, lane = t & 63;
    const int wrp = wave >> 2, wcol = wave & 3;    // wave tile 32r x 64c
    const int l15 = lane & 15, kl = lane >> 4;
    const int srow = t >> 3, s8 = t & 7;           // P staging: 8 thr/row, 16B
    const float* rlb = rl + (size_t)b * Nv;
    const u8* Erow = E + ((size_t)b * Nv + bi * 64 + srow) * Nv + s8 * 16;
    const u8* xtb = xT8 + (size_t)b * 524288;

    auto issueB = [&](int buf, int kt) {   // stage 256 d-rows x 128B (4 gll16)
#pragma unroll
        for (int c = 0; c < 4; ++c) {
            const int row = c * 64 + wave * 8 + (lane >> 3);
            const int slot = (lane & 7) ^ (row & 7);
            gll16(xtb + (size_t)row * Nv + kt * 128 + slot * 16,
                  (char*)Bs[buf] + c * 8192 + wave * 1024);
        }
    };
    auto bfragB = [&](const u8* base, int d, int kk) -> long {
        const int s = kk * 2 + (kl >> 1);
        return *(const long*)(base + d * 128 + ((s ^ (d & 7)) << 4) + ((kl & 1) << 3));
    };

    const float linv_n = rlb[bi * 64 + srow];
    auto wstore = [&](uint4 ev, float4 r0, float4 r1, float4 r2, float4 r3) {
        const u32 o0 = pk4(__builtin_amdgcn_cvt_f32_fp8(ev.x, 0) * (linv_n + r0.x),
                           __builtin_amdgcn_cvt_f32_fp8(ev.x, 1) * (linv_n + r0.y),
                           __builtin_amdgcn_cvt_f32_fp8(ev.x, 2) * (linv_n + r0.z),
                           __builtin_amdgcn_cvt_f32_fp8(ev.x, 3) * (linv_n + r0.w));
        const u32 o1 = pk4(__builtin_amdgcn_cvt_f32_fp8(ev.y, 0) * (linv_n + r1.x),
                           __builtin_amdgcn_cvt_f32_fp8(ev.y, 1) * (linv_n + r1.y),
                           __builtin_amdgcn_cvt_f32_fp8(ev.y, 2) * (linv_n + r1.z),
                           __builtin_amdgcn_cvt_f32_fp8(ev.y, 3) * (linv_n + r1.w));
        const u32 o2 = pk4(__builtin_amdgcn_cvt_f32_fp8(ev.z, 0) * (linv_n + r2.x),
                           __builtin_amdgcn_cvt_f32_fp8(ev.z, 1) * (linv_n + r2.y),
                           __builtin_amdgcn_cvt_f32_fp8(ev.z, 2) * (linv_n + r2.z),
                           __builtin_amdgcn_cvt_f32_fp8(ev.z, 3) * (linv_n + r2.w));
        const u32 o3 = pk4(__builtin_amdgcn_cvt_f32_fp8(ev.w, 0) * (linv_n + r3.x),
                           __builtin_amdgcn_cvt_f32_fp8(ev.w, 1) * (linv_n + r3.y),
                           __builtin_amdgcn_cvt_f32_fp8(ev.w, 2) * (linv_n + r3.z),
                           __builtin_amdgcn_cvt_f32_fp8(ev.w, 3) * (linv_n + r3.w));
        uint4 o = {o0, o1, o2, o3};
        *(uint4*)&Ps[srow * 144 + s8 * 16] = o;
    };

    // prologue
    issueB(0, 0);
    uint4 ev = *(const uint4*)(Erow);
    float4 q0 = *(const float4*)&rlb[s8 * 16];
    float4 q1 = *(const float4*)&rlb[s8 * 16 + 4];
    float4 q2 = *(const float4*)&rlb[s8 * 16 + 8];
    float4 q3 = *(const float4*)&rlb[s8 * 16 + 12];
    __syncthreads();                  // Bs[0] staged
    wstore(ev, q0, q1, q2, q3);
    issueB(1, 1);
    ev = *(const uint4*)(Erow + 128);
    q0 = *(const float4*)&rlb[128 + s8 * 16];
    q1 = *(const float4*)&rlb[128 + s8 * 16 + 4];
    q2 = *(const float4*)&rlb[128 + s8 * 16 + 8];
    q3 = *(const float4*)&rlb[128 + s8 * 16 + 12];
    __syncthreads();                  // Ps(kt0) published, Bs[1] staged

    f32x4 acc[2][4] = {};
    for (int kt = 0; kt < 16; ++kt) {
        // phase 1: MFMA on Ps + Bs[kt&1]; prefetch E/rl for kt+2 (regs only)
        const u8* bs = Bs[kt & 1];
#pragma unroll
        for (int kk = 0; kk < 4; ++kk) {
            const long a0 = *(const long*)&Ps[(wrp * 32 + l15) * 144 + kk * 32 + kl * 8];
            const long a1 = *(const long*)&Ps[(wrp * 32 + 16 + l15) * 144 + kk * 32 + kl * 8];
#pragma unroll
            for (int j = 0; j < 4; ++j) {
                const long bj = bfragB(bs, wcol * 64 + j * 16 + l15, kk);
                acc[0][j] = __builtin_amdgcn_mfma_f32_16x16x32_fp8_fp8(a0, bj, acc[0][j], 0, 0, 0);
                acc[1][j] = __builtin_amdgcn_mfma_f32_16x16x32_fp8_fp8(a1, bj, acc[1][j], 0, 0, 0);
            }
        }
        __syncthreads();
        // phase 2: wstore P(kt+1); stage Bs for kt+2; load E/rl for kt+2
        if (kt < 15) {
            wstore(ev, q0, q1, q2, q3);
            if (kt < 14) {
                issueB(kt & 1, kt + 2);
                const int k2 = (kt + 2) * 128;
                ev = *(const uint4*)(Erow + k2);
                q0 = *(const float4*)&rlb[k2 + s8 * 16];
                q1 = *(const float4*)&rlb[k2 + s8 * 16 + 4];
                q2 = *(const float4*)&rlb[k2 + s8 * 16 + 8];
                q3 = *(const float4*)&rlb[k2 + s8 * 16 + 12];
            }
            __syncthreads();
        }
    }
    // epilogue: v = x - OSC*acc, LN across the 4 col-waves. red overlays Ps.
    float (*red)[4][2] = (float (*)[4][2])(void*)Ps;
    __syncthreads();
    const float* xb = x + ((size_t)b * Nv + bi * 64) * Dv;
    float tv[2][4][4];
#pragma unroll
    for (int i = 0; i < 2; ++i) {
#pragma unroll
        for (int r = 0; r < 4; ++r) {
            const int rr = wrp * 32 + i * 16 + kl * 4 + r;
            float s1 = 0.f, s2 = 0.f;
#pragma unroll
            for (int j = 0; j < 4; ++j) {
                const int cc = wcol * 64 + j * 16 + l15;
                const float v = xb[(size_t)rr * Dv + cc] - OSC * acc[i][j][r];
                tv[i][j][r] = v;
                s1 += v; s2 += v * v;
            }
#pragma unroll
            for (int m = 1; m < 16; m <<= 1) {
                s1 += __shfl_xor(s1, m, 64);
                s2 += __shfl_xor(s2, m, 64);
            }
            if (l15 == 0) { red[rr][wcol][0] = s1; red[rr][wcol][1] = s2; }
        }
    }
    __syncthreads();
#pragma unroll
    for (int i = 0; i < 2; ++i) {
#pragma unroll
        for (int r = 0; r < 4; ++r) {
            const int rr = wrp * 32 + i * 16 + kl * 4 + r;
            const float s1 = red[rr][0][0] + red[rr][1][0] + red[rr][2][0] + red[rr][3][0];
            const float s2 = red[rr][0][1] + red[rr][1][1] + red[rr][2][1] + red[rr][3][1];
            const float mu = s1 * (1.0f / Dv);
            const float var = s2 * (1.0f / Dv) - mu * mu;
            const float rstd = rsqrtf(var + LN_EPS);
#pragma unroll
            for (int j = 0; j < 4; ++j) {
                const int cc = wcol * 64 + j * 16 + l15;
                out[((size_t)b * Nv + bi * 64 + rr) * Dv + cc] =
                    (tv[i][j][r] - mu) * rstd * gamma[cc] + beta[cc];
            }
        }
    }
}

// ---------------------------------------------------------------------------
extern "C" void kernel_launch(void* const* d_in, const int* in_sizes, int n_in,
                              void* d_out, int out_size, void* d_ws, size_t ws_size,
                              hipStream_t stream) {
    const float* x = (const float*)d_in[0];
    const float* gamma = (const float*)d_in[1];
    const float* beta = (const float*)d_in[2];
    float* out = (float*)d_out;
    char* ws = (char*)d_ws;
    u8* xn8 = (u8*)ws;                        // 4.2 MB row-major fp8
    u8* xT8 = (u8*)(ws + 4194304);            // 4.2 MB row-major fp8 [d][n]
    float* rl = (float*)(ws + 8388608);       // 64 KB: PSCALE / l_n
    u8* E = (u8*)(ws + 8454144);              // 33.5 MB fp8, row-major

    k_prepT<<<Bv * (Nv / 64), 512, 0, stream>>>(x, xn8, xT8);
    k_gemm1<<<Bv * (Nv / 64), 512, 0, stream>>>(xn8, E, rl);
    k_gemm2ln<<<Bv * (Nv / 64), 512, 0, stream>>>(E, rl, xT8, x, gamma, beta, out);
}

// Round 14
// 71.196 us; speedup vs baseline: 1.0845x; 1.0845x over previous
//
#include <hip/hip_runtime.h>

namespace {
constexpr int Bv = 8;
constexpr int Nv = 2048;
constexpr int Dv = 256;
constexpr float SCALE = 0.1f;
constexpr float PSCALE = 256.0f;          // P quant scale (fp8 normal range)
constexpr float OSC = SCALE / PSCALE;     // epilogue un-scale
constexpr float LN_EPS = 1e-6f;
constexpr float NORM_EPS = 1e-12f;
}

typedef unsigned char u8;
typedef unsigned int u32;
typedef __attribute__((ext_vector_type(4))) float f32x4;

// global -> LDS direct DMA, 16B/lane. lds base wave-uniform; HW adds lane*16.
__device__ __forceinline__ void gll16(const void* g, void* l) {
    __builtin_amdgcn_global_load_lds(
        (__attribute__((address_space(1))) void*)(uintptr_t)g,
        (__attribute__((address_space(3))) void*)(uintptr_t)l, 16, 0, 0);
}
// pack 4 f32 -> 4 fp8 e4m3 bytes
__device__ __forceinline__ u32 pk4(float a, float b, float c, float d) {
    u32 w = __builtin_amdgcn_cvt_pk_fp8_f32(a, b, 0, false);
    return __builtin_amdgcn_cvt_pk_fp8_f32(c, d, w, true);
}

// ---------------------------------------------------------------------------
// 1) Fused prep. Outputs: xn8 row-major fp8 (L2-normalized rows) and
//    xT8 row-major fp8 (raw x transposed, [b][d][n]). Block = 64 rows x 256 d.
__global__ __launch_bounds__(512) void k_prepT(const float* __restrict__ x,
                                               u8* __restrict__ xn8,
                                               u8* __restrict__ xT8) {
    __shared__ u8 lt[64][272];   // raw-x fp8 [n_local][d]
    const int b = blockIdx.x >> 5;
    const int n0 = (blockIdx.x & 31) * 64;
    const int t = threadIdx.x;
    const int r = t >> 3, c0 = (t & 7) * 32;
    const float* xr = x + ((size_t)b * Nv + n0 + r) * Dv + c0;
    float4 v[8];
    float ss = 0.f;
#pragma unroll
    for (int i = 0; i < 8; ++i) {
        v[i] = ((const float4*)xr)[i];
        ss += v[i].x * v[i].x + v[i].y * v[i].y + v[i].z * v[i].z + v[i].w * v[i].w;
    }
#pragma unroll
    for (int m = 1; m < 8; m <<= 1) ss += __shfl_xor(ss, m, 64);
    const float inv = 1.0f / fmaxf(sqrtf(ss), NORM_EPS);
    u32 wn[8];
#pragma unroll
    for (int i = 0; i < 8; ++i) {
        wn[i] = pk4(v[i].x * inv, v[i].y * inv, v[i].z * inv, v[i].w * inv);
        *(u32*)&lt[r][c0 + i * 4] = pk4(v[i].x, v[i].y, v[i].z, v[i].w);
    }
    {   // xn8 row-major
        uint4 o0 = {wn[0], wn[1], wn[2], wn[3]};
        uint4 o1 = {wn[4], wn[5], wn[6], wn[7]};
        u8* xnr = xn8 + ((size_t)b * Nv + n0 + r) * Dv + c0;
        *(uint4*)xnr = o0;
        *(uint4*)(xnr + 16) = o1;
    }
    __syncthreads();
    {   // xT8 row-major [d][n]: thread handles d = t>>1, n-half h = t&1
        const int d = t >> 1, h = t & 1;
        u32 w2[8];
#pragma unroll
        for (int q = 0; q < 8; ++q) {
            const int nb = h * 32 + q * 4;
            w2[q] = (u32)lt[nb][d] | ((u32)lt[nb + 1][d] << 8) |
                    ((u32)lt[nb + 2][d] << 16) | ((u32)lt[nb + 3][d] << 24);
        }
        uint4 p0 = {w2[0], w2[1], w2[2], w2[3]};
        uint4 p1 = {w2[4], w2[5], w2[6], w2[7]};
        u8* xtr = xT8 + ((size_t)b * Dv + d) * Nv + n0 + h * 32;
        *(uint4*)xtr = p0;
        *(uint4*)(xtr + 16) = p1;
    }
}

// ---------------------------------------------------------------------------
// 2) E = exp(xn@xn^T - 1) fp8, 32-row panels x all 2048 cols. FAT phases:
//    chunk = 256 m-rows (full K staged in one go), single-buffer Bs 64KB,
//    16 barriers total. A-frags in regs; waves 2r x 4c, wave tile 16x64
//    (acc[4], 32 MFMA/phase). eS single (256x40). rl plain write.
__global__ __launch_bounds__(512) void k_gemm1(const u8* __restrict__ xn8,
                                               u8* __restrict__ E,
                                               float* __restrict__ rl) {
    __shared__ u8 Bs[256 * 256];      // 64 KB single
    __shared__ u8 eS[256 * 40];       // 10 KB [m-col][32 n + pad8]
    __shared__ float red[32][4];      // 0.5 KB
    const int wg = blockIdx.x;        // 512: XCD owns one batch
    const int b = wg & 7, bi = wg >> 3;            // bi 0..63 (32-row panel)
    const int t = threadIdx.x;
    const int wave = t >> 6, lane = t & 63;
    const int wr = wave >> 2, wc = wave & 3;       // wave tile 16r x 64c
    const int l15 = lane & 15, kl = lane >> 4;
    const u8* xb = xn8 + (size_t)b * (Nv * Dv);
    u8* Eb = E + (size_t)b * Nv * Nv;

    auto stage = [&](int ch) {   // 256 rows x 256B, swizzled source, 8 gll16
#pragma unroll
        for (int c = 0; c < 8; ++c) {
            const int row = wave * 32 + c * 4 + (lane >> 4);
            const int slot = (lane & 15) ^ (row & 15);
            gll16(xb + (size_t)(ch * 256 + row) * Dv + slot * 16,
                  Bs + wave * 8192 + c * 1024);
        }
    };
    auto bfrag = [&](int row, int kk) -> long {
        const int slot = kk * 2 + (kl >> 1);
        return *(const long*)(Bs + row * 256 +
                              ((slot ^ (row & 15)) << 4) + ((kl & 1) << 3));
    };

    const int ch0 = bi >> 3;   // chunk containing this panel's rows
    stage(ch0);
    __syncthreads();
    long af[8];
    {
        const int arow = (bi & 7) * 32 + wr * 16 + l15;
#pragma unroll
        for (int kk = 0; kk < 8; ++kk) af[kk] = bfrag(arow, kk);
    }
    float rs[4] = {0.f, 0.f, 0.f, 0.f};
    for (int cc = 0; cc < 8; ++cc) {
        const int ch = (ch0 + cc) & 7;
        // phase 1: MFMA (32/wave) + exp -> eS
        f32x4 acc[4] = {};
#pragma unroll
        for (int kk = 0; kk < 8; ++kk) {
#pragma unroll
            for (int j = 0; j < 4; ++j) {
                const long bj = bfrag(wc * 64 + j * 16 + l15, kk);
                acc[j] = __builtin_amdgcn_mfma_f32_16x16x32_fp8_fp8(af[kk], bj, acc[j], 0, 0, 0);
            }
        }
#pragma unroll
        for (int j = 0; j < 4; ++j) {
            const int col = wc * 64 + j * 16 + l15;
            const float e0 = __expf(acc[j][0] - 1.0f);
            const float e1 = __expf(acc[j][1] - 1.0f);
            const float e2 = __expf(acc[j][2] - 1.0f);
            const float e3 = __expf(acc[j][3] - 1.0f);
            rs[0] += e0; rs[1] += e1; rs[2] += e2; rs[3] += e3;
            *(u32*)&eS[col * 40 + wr * 16 + kl * 4] = pk4(e0, e1, e2, e3);
        }
        __syncthreads();   // eS complete; Bs fully consumed
        // phase 2: E-store (transposed via symmetry) + stage next chunk
        {
            const int c2 = t >> 1, half = t & 1;
            *(uint4*)&Eb[(size_t)(ch * 256 + c2) * Nv + bi * 32 + half * 16] =
                *(const uint4*)&eS[c2 * 40 + half * 16];
        }
        if (cc < 7) stage((ch0 + cc + 1) & 7);
        __syncthreads();   // Bs staged; eS consumed
    }
    // rl reduction: plain write, no atomics.
#pragma unroll
    for (int r = 0; r < 4; ++r) {
        float v = rs[r];
#pragma unroll
        for (int m = 1; m < 16; m <<= 1) v += __shfl_xor(v, m, 64);
        if (l15 == 0) red[wr * 16 + kl * 4 + r][wc] = v;
    }
    __syncthreads();
    if (t < 32)
        rl[b * Nv + bi * 32 + t] =
            PSCALE * __builtin_amdgcn_rcpf(red[t][0] + red[t][1] + red[t][2] + red[t][3]);
}

// ---------------------------------------------------------------------------
// 3) x_neg = P @ x, P[n,m] = E[n,m]*(rl_n + rl_m), fused LN epilogue.
//    FAT phases: BK=256 (8 kt), single Bs 64KB, single Ps (stride 264),
//    16 barriers. Waves 1r x 8c, wave tile 32x32 (acc[2][2]); A-frags
//    pre-read to regs each kt so Ps single-buffer is safe.
__global__ __launch_bounds__(512) void k_gemm2ln(const u8* __restrict__ E,
                                                 const float* __restrict__ rl,
                                                 const u8* __restrict__ xT8,
                                                 const float* __restrict__ x,
                                                 const float* __restrict__ gamma,
                                                 const float* __restrict__ beta,
                                                 float* __restrict__ out) {
    __shared__ u8 Bs[256 * 256];      // 64 KB single: 256 d-rows x 256B m-window
    __shared__ u8 Ps[32 * 264];       // 8.25 KB single
    __shared__ float red[32][8][2];   // 2 KB
    const int wg = blockIdx.x;        // 512: XCD owns one batch
    const int swz = (wg & 7) * 64 + (wg >> 3);
    const int b = swz >> 6, bi = swz & 63;         // 32-row panel
    const int t = threadIdx.x;
    const int wave = t >> 6, lane = t & 63;
    const int l15 = lane & 15, kl = lane >> 4;
    const int srow = t >> 4, s16 = t & 15;         // P staging: 16 thr/row
    const float* rlb = rl + (size_t)b * Nv;
    const u8* Erow = E + ((size_t)b * Nv + bi * 32 + srow) * Nv + s16 * 16;
    const u8* xtb = xT8 + (size_t)b * 524288;

    auto stage = [&](int kt) {   // 256 d-rows x 256B, 8 gll16
#pragma unroll
        for (int c = 0; c < 8; ++c) {
            const int row = wave * 32 + c * 4 + (lane >> 4);
            const int slot = (lane & 15) ^ (row & 15);
            gll16(xtb + (size_t)row * Nv + kt * 256 + slot * 16,
                  Bs + wave * 8192 + c * 1024);
        }
    };
    auto bfragB = [&](int d, int kk) -> long {
        const int slot = kk * 2 + (kl >> 1);
        return *(const long*)(Bs + d * 256 +
                              ((slot ^ (d & 15)) << 4) + ((kl & 1) << 3));
    };

    const float linv_n = rlb[bi * 32 + srow];
    auto wstore = [&](uint4 ev, float4 r0, float4 r1, float4 r2, float4 r3) {
        const u32 o0 = pk4(__builtin_amdgcn_cvt_f32_fp8(ev.x, 0) * (linv_n + r0.x),
                           __builtin_amdgcn_cvt_f32_fp8(ev.x, 1) * (linv_n + r0.y),
                           __builtin_amdgcn_cvt_f32_fp8(ev.x, 2) * (linv_n + r0.z),
                           __builtin_amdgcn_cvt_f32_fp8(ev.x, 3) * (linv_n + r0.w));
        const u32 o1 = pk4(__builtin_amdgcn_cvt_f32_fp8(ev.y, 0) * (linv_n + r1.x),
                           __builtin_amdgcn_cvt_f32_fp8(ev.y, 1) * (linv_n + r1.y),
                           __builtin_amdgcn_cvt_f32_fp8(ev.y, 2) * (linv_n + r1.z),
                           __builtin_amdgcn_cvt_f32_fp8(ev.y, 3) * (linv_n + r1.w));
        const u32 o2 = pk4(__builtin_amdgcn_cvt_f32_fp8(ev.z, 0) * (linv_n + r2.x),
                           __builtin_amdgcn_cvt_f32_fp8(ev.z, 1) * (linv_n + r2.y),
                           __builtin_amdgcn_cvt_f32_fp8(ev.z, 2) * (linv_n + r2.z),
                           __builtin_amdgcn_cvt_f32_fp8(ev.z, 3) * (linv_n + r2.w));
        const u32 o3 = pk4(__builtin_amdgcn_cvt_f32_fp8(ev.w, 0) * (linv_n + r3.x),
                           __builtin_amdgcn_cvt_f32_fp8(ev.w, 1) * (linv_n + r3.y),
                           __builtin_amdgcn_cvt_f32_fp8(ev.w, 2) * (linv_n + r3.z),
                           __builtin_amdgcn_cvt_f32_fp8(ev.w, 3) * (linv_n + r3.w));
        uint2 lo = {o0, o1}, hi = {o2, o3};
        *(uint2*)&Ps[srow * 264 + s16 * 16] = lo;
        *(uint2*)&Ps[srow * 264 + s16 * 16 + 8] = hi;
    };

    // prologue
    stage(0);
    uint4 ev = *(const uint4*)(Erow);
    float4 q0 = *(const float4*)&rlb[s16 * 16];
    float4 q1 = *(const float4*)&rlb[s16 * 16 + 4];
    float4 q2 = *(const float4*)&rlb[s16 * 16 + 8];
    float4 q3 = *(const float4*)&rlb[s16 * 16 + 12];
    __syncthreads();                  // Bs(0) staged, ev(0) loaded
    wstore(ev, q0, q1, q2, q3);       // Ps <- P(kt=0)
    ev = *(const uint4*)(Erow + 256);
    q0 = *(const float4*)&rlb[256 + s16 * 16];
    q1 = *(const float4*)&rlb[256 + s16 * 16 + 4];
    q2 = *(const float4*)&rlb[256 + s16 * 16 + 8];
    q3 = *(const float4*)&rlb[256 + s16 * 16 + 12];
    __syncthreads();                  // Ps(0) published

    f32x4 acc[2][2] = {};
    for (int kt = 0; kt < 8; ++kt) {
        // phase 1: A-frags to regs, then 8kk x 4 MFMA
        long af2[2][8];
#pragma unroll
        for (int i = 0; i < 2; ++i)
#pragma unroll
            for (int kk = 0; kk < 8; ++kk)
                af2[i][kk] = *(const long*)&Ps[(i * 16 + l15) * 264 + kk * 32 + kl * 8];
#pragma unroll
        for (int kk = 0; kk < 8; ++kk) {
            const long b0 = bfragB(wave * 32 + l15, kk);
            const long b1 = bfragB(wave * 32 + 16 + l15, kk);
            acc[0][0] = __builtin_amdgcn_mfma_f32_16x16x32_fp8_fp8(af2[0][kk], b0, acc[0][0], 0, 0, 0);
            acc[0][1] = __builtin_amdgcn_mfma_f32_16x16x32_fp8_fp8(af2[0][kk], b1, acc[0][1], 0, 0, 0);
            acc[1][0] = __builtin_amdgcn_mfma_f32_16x16x32_fp8_fp8(af2[1][kk], b0, acc[1][0], 0, 0, 0);
            acc[1][1] = __builtin_amdgcn_mfma_f32_16x16x32_fp8_fp8(af2[1][kk], b1, acc[1][1], 0, 0, 0);
        }
        __syncthreads();              // Ps & Bs fully consumed
        // phase 2: publish P(kt+1), stage B(kt+1), prefetch E/rl(kt+2)
        if (kt < 7) {
            wstore(ev, q0, q1, q2, q3);
            if (kt < 6) {
                const int k2 = (kt + 2) * 256;
                ev = *(const uint4*)(Erow + k2);
                q0 = *(const float4*)&rlb[k2 + s16 * 16];
                q1 = *(const float4*)&rlb[k2 + s16 * 16 + 4];
                q2 = *(const float4*)&rlb[k2 + s16 * 16 + 8];
                q3 = *(const float4*)&rlb[k2 + s16 * 16 + 12];
            }
            stage(kt + 1);
            __syncthreads();          // Bs(kt+1) staged, Ps(kt+1) published
        }
    }
    // epilogue: v = x - OSC*acc, LN across the 8 col-waves.
    const float* xb = x + ((size_t)b * Nv + bi * 32) * Dv;
    float tv[2][2][4];
#pragma unroll
    for (int i = 0; i < 2; ++i) {
#pragma unroll
        for (int r = 0; r < 4; ++r) {
            const int rr = i * 16 + kl * 4 + r;
            float s1 = 0.f, s2 = 0.f;
#pragma unroll
            for (int j = 0; j < 2; ++j) {
                const int cc = wave * 32 + j * 16 + l15;
                const float v = xb[(size_t)rr * Dv + cc] - OSC * acc[i][j][r];
                tv[i][j][r] = v;
                s1 += v; s2 += v * v;
            }
#pragma unroll
            for (int m = 1; m < 16; m <<= 1) {
                s1 += __shfl_xor(s1, m, 64);
                s2 += __shfl_xor(s2, m, 64);
            }
            if (l15 == 0) { red[rr][wave][0] = s1; red[rr][wave][1] = s2; }
        }
    }
    __syncthreads();
#pragma unroll
    for (int i = 0; i < 2; ++i) {
#pragma unroll
        for (int r = 0; r < 4; ++r) {
            const int rr = i * 16 + kl * 4 + r;
            float s1 = 0.f, s2 = 0.f;
#pragma unroll
            for (int w = 0; w < 8; ++w) { s1 += red[rr][w][0]; s2 += red[rr][w][1]; }
            const float mu = s1 * (1.0f / Dv);
            const float var = s2 * (1.0f / Dv) - mu * mu;
            const float rstd = rsqrtf(var + LN_EPS);
#pragma unroll
            for (int j = 0; j < 2; ++j) {
                const int cc = wave * 32 + j * 16 + l15;
                out[((size_t)b * Nv + bi * 32 + rr) * Dv + cc] =
                    (tv[i][j][r] - mu) * rstd * gamma[cc] + beta[cc];
            }
        }
    }
}

// ---------------------------------------------------------------------------
extern "C" void kernel_launch(void* const* d_in, const int* in_sizes, int n_in,
                              void* d_out, int out_size, void* d_ws, size_t ws_size,
                              hipStream_t stream) {
    const float* x = (const float*)d_in[0];
    const float* gamma = (const float*)d_in[1];
    const float* beta = (const float*)d_in[2];
    float* out = (float*)d_out;
    char* ws = (char*)d_ws;
    u8* xn8 = (u8*)ws;                        // 4.2 MB row-major fp8
    u8* xT8 = (u8*)(ws + 4194304);            // 4.2 MB row-major fp8 [d][n]
    float* rl = (float*)(ws + 8388608);       // 64 KB: PSCALE / l_n
    u8* E = (u8*)(ws + 8454144);              // 33.5 MB fp8, row-major

    k_prepT<<<Bv * (Nv / 64), 512, 0, stream>>>(x, xn8, xT8);
    k_gemm1<<<Bv * (Nv / 32), 512, 0, stream>>>(xn8, E, rl);
    k_gemm2ln<<<Bv * (Nv / 32), 512, 0, stream>>>(E, rl, xT8, x, gamma, beta, out);
}

// Round 15
// 66.140 us; speedup vs baseline: 1.1675x; 1.0764x over previous
//
#include <hip/hip_runtime.h>

namespace {
constexpr int Bv = 8;
constexpr int Nv = 2048;
constexpr int Dv = 256;
constexpr float SCALE = 0.1f;
constexpr float PSCALE = 256.0f;          // P quant scale (fp8 normal range)
constexpr float OSC = SCALE / PSCALE;     // epilogue un-scale
constexpr float LN_EPS = 1e-6f;
constexpr float NORM_EPS = 1e-12f;
}

typedef unsigned char u8;
typedef unsigned int u32;
typedef __attribute__((ext_vector_type(4))) float f32x4;

// global -> LDS direct DMA, 16B/lane. lds base wave-uniform; HW adds lane*16.
__device__ __forceinline__ void gll16(const void* g, void* l) {
    __builtin_amdgcn_global_load_lds(
        (__attribute__((address_space(1))) void*)(uintptr_t)g,
        (__attribute__((address_space(3))) void*)(uintptr_t)l, 16, 0, 0);
}
// pack 4 f32 -> 4 fp8 e4m3 bytes
__device__ __forceinline__ u32 pk4(float a, float b, float c, float d) {
    u32 w = __builtin_amdgcn_cvt_pk_fp8_f32(a, b, 0, false);
    return __builtin_amdgcn_cvt_pk_fp8_f32(c, d, w, true);
}

// ---------------------------------------------------------------------------
// 1) Fused prep. Outputs: xn8 row-major fp8 (L2-normalized rows) and
//    xT8 row-major fp8 (raw x transposed, [b][d][n]). Block = 64 rows x 256 d.
__global__ __launch_bounds__(512) void k_prepT(const float* __restrict__ x,
                                               u8* __restrict__ xn8,
                                               u8* __restrict__ xT8) {
    __shared__ u8 lt[64][272];   // raw-x fp8 [n_local][d]
    const int b = blockIdx.x >> 5;
    const int n0 = (blockIdx.x & 31) * 64;
    const int t = threadIdx.x;
    const int r = t >> 3, c0 = (t & 7) * 32;
    const float* xr = x + ((size_t)b * Nv + n0 + r) * Dv + c0;
    float4 v[8];
    float ss = 0.f;
#pragma unroll
    for (int i = 0; i < 8; ++i) {
        v[i] = ((const float4*)xr)[i];
        ss += v[i].x * v[i].x + v[i].y * v[i].y + v[i].z * v[i].z + v[i].w * v[i].w;
    }
#pragma unroll
    for (int m = 1; m < 8; m <<= 1) ss += __shfl_xor(ss, m, 64);
    const float inv = 1.0f / fmaxf(sqrtf(ss), NORM_EPS);
    u32 wn[8];
#pragma unroll
    for (int i = 0; i < 8; ++i) {
        wn[i] = pk4(v[i].x * inv, v[i].y * inv, v[i].z * inv, v[i].w * inv);
        *(u32*)&lt[r][c0 + i * 4] = pk4(v[i].x, v[i].y, v[i].z, v[i].w);
    }
    {   // xn8 row-major
        uint4 o0 = {wn[0], wn[1], wn[2], wn[3]};
        uint4 o1 = {wn[4], wn[5], wn[6], wn[7]};
        u8* xnr = xn8 + ((size_t)b * Nv + n0 + r) * Dv + c0;
        *(uint4*)xnr = o0;
        *(uint4*)(xnr + 16) = o1;
    }
    __syncthreads();
    {   // xT8 row-major [d][n]: thread handles d = t>>1, n-half h = t&1
        const int d = t >> 1, h = t & 1;
        u32 w2[8];
#pragma unroll
        for (int q = 0; q < 8; ++q) {
            const int nb = h * 32 + q * 4;
            w2[q] = (u32)lt[nb][d] | ((u32)lt[nb + 1][d] << 8) |
                    ((u32)lt[nb + 2][d] << 16) | ((u32)lt[nb + 3][d] << 24);
        }
        uint4 p0 = {w2[0], w2[1], w2[2], w2[3]};
        uint4 p1 = {w2[4], w2[5], w2[6], w2[7]};
        u8* xtr = xT8 + ((size_t)b * Dv + d) * Nv + n0 + h * 32;
        *(uint4*)xtr = p0;
        *(uint4*)(xtr + 16) = p1;
    }
}

// ---------------------------------------------------------------------------
// 2) E = exp(xn@xn^T - 1) fp8, row-panel blocks: 32 rows x ALL 2048 cols.
//    A-frags in registers; B gll16-staged, 256B rows, slot^(row&15) swizzle,
//    dbuf over 16 chunks of 128 cols. Writes rl[n] = PSCALE/l_n directly
//    (block owns full rows — no atomics). E stored via col-major LDS restage.
__global__ __launch_bounds__(512, 4) void k_gemm1(const u8* __restrict__ xn8,
                                                  u8* __restrict__ E,
                                                  float* __restrict__ rl) {
    __shared__ u8 Bs[2][128 * 256];   // 2 x 32 KB
    __shared__ u8 eS[2][128 * 40];    // [m-col][32 n + pad8], 2 x 5 KB
    __shared__ float red[32][4];
    const int wg = blockIdx.x;        // 512: XCD owns one batch
    const int b = wg & 7, bi = wg >> 3;            // bi 0..63 (32-row panel)
    const int t = threadIdx.x;
    const int wave = t >> 6, lane = t & 63;
    const int wr = wave >> 2, wc = wave & 3;       // wave tile 16r x 32c
    const int l15 = lane & 15, kl = lane >> 4;
    const u8* xb = xn8 + (size_t)b * (Nv * Dv);

    auto stageB = [&](int buf, int ch) {   // 128 rows x 256B
#pragma unroll
        for (int c = 0; c < 4; ++c) {
            const int row = wave * 16 + c * 4 + (lane >> 4);
            const int slot = (lane & 15) ^ (row & 15);
            gll16(xb + (size_t)(ch * 128 + row) * Dv + slot * 16,
                  Bs[buf] + wave * 4096 + c * 1024);
        }
    };
    auto bfrag = [&](const u8* base, int row, int kk) -> long {
        const int slot = kk * 2 + (kl >> 1);
        return *(const long*)(base + row * 256 +
                              ((slot ^ (row & 15)) << 4) + ((kl & 1) << 3));
    };

    const int ch0 = bi >> 2;   // chunk containing this panel's own rows
    stageB(0, ch0);
    __syncthreads();
    long af[8];
    {
        const int arow = (bi & 3) * 32 + wr * 16 + l15;
#pragma unroll
        for (int kk = 0; kk < 8; ++kk) af[kk] = bfrag(Bs[0], arow, kk);
    }
    float rs[4] = {0.f, 0.f, 0.f, 0.f};
    u8* Eb = E + (size_t)b * Nv * Nv;
    int cur = 0;
    for (int cc = 0; cc < 16; ++cc) {
        const int ch = (ch0 + cc) & 15;
        if (cc < 15) stageB(cur ^ 1, (ch0 + cc + 1) & 15);
        f32x4 acc[2] = {};
#pragma unroll
        for (int kk = 0; kk < 8; ++kk) {
            const long b0 = bfrag(Bs[cur], wc * 32 + l15, kk);
            const long b1 = bfrag(Bs[cur], wc * 32 + 16 + l15, kk);
            acc[0] = __builtin_amdgcn_mfma_f32_16x16x32_fp8_fp8(af[kk], b0, acc[0], 0, 0, 0);
            acc[1] = __builtin_amdgcn_mfma_f32_16x16x32_fp8_fp8(af[kk], b1, acc[1], 0, 0, 0);
        }
#pragma unroll
        for (int j = 0; j < 2; ++j) {
            const int col = wc * 32 + j * 16 + l15;   // m within chunk
            const float e0 = __expf(acc[j][0] - 1.0f);
            const float e1 = __expf(acc[j][1] - 1.0f);
            const float e2 = __expf(acc[j][2] - 1.0f);
            const float e3 = __expf(acc[j][3] - 1.0f);
            rs[0] += e0; rs[1] += e1; rs[2] += e2; rs[3] += e3;
            *(u32*)&eS[cur][col * 40 + wr * 16 + kl * 4] = pk4(e0, e1, e2, e3);
        }
        __syncthreads();   // Bs[cur^1] staged; eS[cur] complete
        {   // store: E[m = ch*128 + c][bi*32 + 0..31], 8B per thread
            const int c = t >> 2, sg = t & 3;
            *(uint2*)&Eb[(size_t)(ch * 128 + c) * Nv + bi * 32 + sg * 8] =
                *(const uint2*)&eS[cur][c * 40 + sg * 8];
        }
        cur ^= 1;
    }
#pragma unroll
    for (int r = 0; r < 4; ++r) {
        float v = rs[r];
#pragma unroll
        for (int m = 1; m < 16; m <<= 1) v += __shfl_xor(v, m, 64);
        if (l15 == 0) red[wr * 16 + kl * 4 + r][wc] = v;
    }
    __syncthreads();
    if (t < 32)
        rl[b * Nv + bi * 32 + t] =
            PSCALE * __builtin_amdgcn_rcpf(red[t][0] + red[t][1] + red[t][2] + red[t][3]);
}

// ---------------------------------------------------------------------------
// 3) x_neg = P @ x, P[n,m] = E[n,m]*(rl_n + rl_m) built per-kt in Ps (stride
//    136 = 17 odd 8B-slots -> conflict-free A-frags). B staged per-kt via
//    gll16 into swizzled LDS (256 d-rows x 128B, slot^(row&7)), dbuf.
//    Wave tile 32x32 (acc[2][2]) so each staged byte feeds 2 MFMAs.
//    Fused: out = LayerNorm(x - OSC*acc)*gamma + beta. 2 blocks/CU.
__global__ __launch_bounds__(512) void k_gemm2ln(const u8* __restrict__ E,
                                                 const float* __restrict__ rl,
                                                 const u8* __restrict__ xT8,
                                                 const float* __restrict__ x,
                                                 const float* __restrict__ gamma,
                                                 const float* __restrict__ beta,
                                                 float* __restrict__ out) {
    __shared__ u8 Bs[2][256 * 128];   // 64 KB
    __shared__ u8 Ps[2][32 * 136];    // 8.5 KB
    __shared__ float red[32][8][2];   // 2 KB
    const int wg = blockIdx.x;        // 512: XCD owns one batch
    const int swz = (wg & 7) * 64 + (wg >> 3);
    const int b = swz >> 6, bi = swz & 63;         // 32-row panel
    const int t = threadIdx.x;
    const int wave = t >> 6, lane = t & 63;
    const int l15 = lane & 15, kl = lane >> 4;
    const int srow = t >> 4, s16 = t & 15;         // P staging: 16 thr/row
    const float* rlb = rl + (size_t)b * Nv;
    const u8* Erow = E + ((size_t)b * Nv + bi * 32 + srow) * Nv + s16 * 8;
    const u8* xtb = xT8 + (size_t)b * 524288;

    auto issueB = [&](int buf, int kt) {   // stage 256 d-rows x 128B
#pragma unroll
        for (int c = 0; c < 4; ++c) {
            const int row = c * 64 + wave * 8 + (lane >> 3);
            const int slot = (lane & 7) ^ (row & 7);
            gll16(xtb + (size_t)row * Nv + kt * 128 + slot * 16,
                  (char*)Bs[buf] + c * 8192 + wave * 1024);
        }
    };
    auto bfragB = [&](const u8* base, int d, int kk) -> long {
        const int s = kk * 2 + (kl >> 1);
        return *(const long*)(base + d * 128 + ((s ^ (d & 7)) << 4) + ((kl & 1) << 3));
    };
    auto afrag = [&](const u8* base, int row, int kk) -> long {
        return *(const long*)(base + row * 136 + kk * 32 + kl * 8);
    };

    const float linv_n = rlb[bi * 32 + srow];
    auto wstore = [&](u8* pbuf, uint2 ev, float4 ra, float4 rb) {
        const u32 o0 = pk4(__builtin_amdgcn_cvt_f32_fp8(ev.x, 0) * (linv_n + ra.x),
                           __builtin_amdgcn_cvt_f32_fp8(ev.x, 1) * (linv_n + ra.y),
                           __builtin_amdgcn_cvt_f32_fp8(ev.x, 2) * (linv_n + ra.z),
                           __builtin_amdgcn_cvt_f32_fp8(ev.x, 3) * (linv_n + ra.w));
        const u32 o1 = pk4(__builtin_amdgcn_cvt_f32_fp8(ev.y, 0) * (linv_n + rb.x),
                           __builtin_amdgcn_cvt_f32_fp8(ev.y, 1) * (linv_n + rb.y),
                           __builtin_amdgcn_cvt_f32_fp8(ev.y, 2) * (linv_n + rb.z),
                           __builtin_amdgcn_cvt_f32_fp8(ev.y, 3) * (linv_n + rb.w));
        uint2 o = {o0, o1};
        *(uint2*)(pbuf + srow * 136 + s16 * 8) = o;
    };

    issueB(0, 0);
    uint2 evB = *(const uint2*)(Erow);
    float4 raB = *(const float4*)&rlb[s16 * 8];
    float4 rbB = *(const float4*)&rlb[s16 * 8 + 4];
    wstore(Ps[0], evB, raB, rbB);
    evB = *(const uint2*)(Erow + 128);
    uint2 evC = *(const uint2*)(Erow + 256);
    raB = *(const float4*)&rlb[128 + s16 * 8];
    rbB = *(const float4*)&rlb[128 + s16 * 8 + 4];
    __syncthreads();                   // Bs[0] (vmcnt drain) + Ps[0] ready

    f32x4 acc[2][2] = {};
    int cur = 0;
    for (int kt = 0; kt < 16; ++kt) {
        if (kt < 15) issueB(cur ^ 1, kt + 1);
#pragma unroll
        for (int kk = 0; kk < 4; ++kk) {
            const long a0 = afrag(Ps[cur], l15, kk);
            const long a1 = afrag(Ps[cur], 16 + l15, kk);
            const long b0 = bfragB(Bs[cur], wave * 32 + l15, kk);
            const long b1 = bfragB(Bs[cur], wave * 32 + 16 + l15, kk);
            acc[0][0] = __builtin_amdgcn_mfma_f32_16x16x32_fp8_fp8(a0, b0, acc[0][0], 0, 0, 0);
            acc[0][1] = __builtin_amdgcn_mfma_f32_16x16x32_fp8_fp8(a0, b1, acc[0][1], 0, 0, 0);
            acc[1][0] = __builtin_amdgcn_mfma_f32_16x16x32_fp8_fp8(a1, b0, acc[1][0], 0, 0, 0);
            acc[1][1] = __builtin_amdgcn_mfma_f32_16x16x32_fp8_fp8(a1, b1, acc[1][1], 0, 0, 0);
        }
        if (kt < 15) {
            wstore(Ps[cur ^ 1], evB, raB, rbB);
            evB = evC;
            if (kt < 14) {
                evC = *(const uint2*)(Erow + (kt + 2) * 128);
                raB = *(const float4*)&rlb[(kt + 1) * 128 + s16 * 8];
                rbB = *(const float4*)&rlb[(kt + 1) * 128 + s16 * 8 + 4];
            }
        }
        __syncthreads();
        cur ^= 1;
    }
    // epilogue: v = x - OSC*acc, LN across the 8 waves (32 cols each).
    const float* xb = x + ((size_t)b * Nv + bi * 32) * Dv;
    float tv[2][2][4];
#pragma unroll
    for (int i = 0; i < 2; ++i) {
#pragma unroll
        for (int r = 0; r < 4; ++r) {
            const int rr = i * 16 + kl * 4 + r;
            float s1 = 0.f, s2 = 0.f;
#pragma unroll
            for (int j = 0; j < 2; ++j) {
                const int cc = wave * 32 + j * 16 + l15;
                const float v = xb[(size_t)rr * Dv + cc] - OSC * acc[i][j][r];
                tv[i][j][r] = v;
                s1 += v; s2 += v * v;
            }
#pragma unroll
            for (int m = 1; m < 16; m <<= 1) {
                s1 += __shfl_xor(s1, m, 64);
                s2 += __shfl_xor(s2, m, 64);
            }
            if (l15 == 0) { red[rr][wave][0] = s1; red[rr][wave][1] = s2; }
        }
    }
    __syncthreads();
#pragma unroll
    for (int i = 0; i < 2; ++i) {
#pragma unroll
        for (int r = 0; r < 4; ++r) {
            const int rr = i * 16 + kl * 4 + r;
            float s1 = 0.f, s2 = 0.f;
#pragma unroll
            for (int w = 0; w < 8; ++w) { s1 += red[rr][w][0]; s2 += red[rr][w][1]; }
            const float mu = s1 * (1.0f / Dv);
            const float var = s2 * (1.0f / Dv) - mu * mu;
            const float rstd = rsqrtf(var + LN_EPS);
#pragma unroll
            for (int j = 0; j < 2; ++j) {
                const int cc = wave * 32 + j * 16 + l15;
                out[((size_t)b * Nv + bi * 32 + rr) * Dv + cc] =
                    (tv[i][j][r] - mu) * rstd * gamma[cc] + beta[cc];
            }
        }
    }
}

// ---------------------------------------------------------------------------
extern "C" void kernel_launch(void* const* d_in, const int* in_sizes, int n_in,
                              void* d_out, int out_size, void* d_ws, size_t ws_size,
                              hipStream_t stream) {
    const float* x = (const float*)d_in[0];
    const float* gamma = (const float*)d_in[1];
    const float* beta = (const float*)d_in[2];
    float* out = (float*)d_out;
    char* ws = (char*)d_ws;
    u8* xn8 = (u8*)ws;                        // 4.2 MB row-major fp8
    u8* xT8 = (u8*)(ws + 4194304);            // 4.2 MB row-major fp8 [d][n]
    float* rl = (float*)(ws + 8388608);       // 64 KB: PSCALE / l_n
    u8* E = (u8*)(ws + 8454144);              // 33.5 MB fp8, row-major

    k_prepT<<<Bv * (Nv / 64), 512, 0, stream>>>(x, xn8, xT8);
    k_gemm1<<<Bv * (Nv / 32), 512, 0, stream>>>(xn8, E, rl);
    k_gemm2ln<<<Bv * (Nv / 32), 512, 0, stream>>>(E, rl, xT8, x, gamma, beta, out);
}